// Round 1
// baseline (142.241 us; speedup 1.0000x reference)
//
#include <hip/hip_runtime.h>

typedef __attribute__((ext_vector_type(8))) short short8;
typedef __attribute__((ext_vector_type(4))) float f32x4;
typedef __attribute__((ext_vector_type(4))) int   i32x4;

#define NN 8192
#define FIN 128
#define FOUT 64
#define LRELU_ALPHA 0.2f

__device__ __forceinline__ unsigned short f2bf(float x) {
    unsigned u = __float_as_uint(x);
    unsigned r = (u + 0x7FFFu + ((u >> 16) & 1u)) >> 16;  // RNE
    return (unsigned short)r;
}

// ---------------------------------------------------------------------------
// Kernel 1: h = inp @ W  (8192x128 @ 128x64), s1 = h@a1, s2 = h@a2,
//           ht_bf16[f][i] = bf16(h[i][f])  (transposed for MFMA B-fragments)
// Block: 256 threads = 4 rows x 64 f-lanes. Grid: 2048.
// ---------------------------------------------------------------------------
__global__ __launch_bounds__(256) void gat_prep(
    const float* __restrict__ inp, const float* __restrict__ W,
    const float* __restrict__ a,
    unsigned short* __restrict__ ht, float* __restrict__ s1, float* __restrict__ s2)
{
    __shared__ float Wl[FIN * FOUT];   // 32 KB
    __shared__ float il[4 * FIN];      // 2 KB
    const int t = threadIdx.x;
    const int i0 = blockIdx.x * 4;

    #pragma unroll
    for (int k = 0; k < (FIN * FOUT) / 256; ++k)
        Wl[t + 256 * k] = W[t + 256 * k];
    #pragma unroll
    for (int k = 0; k < (4 * FIN) / 256; ++k)
        il[t + 256 * k] = inp[(size_t)i0 * FIN + t + 256 * k];
    __syncthreads();

    const int r = t >> 6;        // local row 0..3
    const int f = t & 63;        // output feature
    float acc = 0.f;
    #pragma unroll 8
    for (int k = 0; k < FIN; ++k)
        acc = fmaf(il[r * FIN + k], Wl[k * FOUT + f], acc);

    // s1/s2 via wave reduction over the 64 f-lanes
    float v1 = acc * a[f];
    float v2 = acc * a[FOUT + f];
    #pragma unroll
    for (int off = 32; off; off >>= 1) {
        v1 += __shfl_xor(v1, off, 64);
        v2 += __shfl_xor(v2, off, 64);
    }
    const int i = i0 + r;
    if (f == 0) { s1[i] = v1; s2[i] = v2; }
    ht[(size_t)f * NN + i] = f2bf(acc);
}

// ---------------------------------------------------------------------------
// Kernel 2: s2max = max_j s2[j]  (1 block)
// ---------------------------------------------------------------------------
__global__ __launch_bounds__(256) void gat_s2max(const float* __restrict__ s2,
                                                 float* __restrict__ s2m)
{
    __shared__ float red[256];
    float m = -1e30f;
    for (int idx = threadIdx.x; idx < NN; idx += 256) m = fmaxf(m, s2[idx]);
    red[threadIdx.x] = m;
    __syncthreads();
    #pragma unroll
    for (int s = 128; s; s >>= 1) {
        if (threadIdx.x < s) red[threadIdx.x] = fmaxf(red[threadIdx.x], red[threadIdx.x + s]);
        __syncthreads();
    }
    if (threadIdx.x == 0) s2m[0] = red[0];
}

// ---------------------------------------------------------------------------
// Kernel 3 (hot): per (row-block of 64, j-range) compute p = adj ? exp(lrelu(
// s1_i+s2_j) - M_i) : 0 directly in MFMA A-fragment layout, accumulate
// p @ h via mfma_f32_16x16x32_bf16, write fp32 partials (acc, l) to ws.
// Block: 256 threads = 4 waves x 16 rows each. Grid: (128, JS).
// ---------------------------------------------------------------------------
__global__ __launch_bounds__(256, 4) void gat_attn(
    const int* __restrict__ adj, const unsigned short* __restrict__ ht,
    const float* __restrict__ s1, const float* __restrict__ s2,
    const float* __restrict__ s2m,
    float* __restrict__ pacc, float* __restrict__ pl, int jlen)
{
    const int w    = threadIdx.x >> 6;   // wave 0..3 -> rows w*16..w*16+15
    const int lane = threadIdx.x & 63;
    const int lo   = lane & 15;          // A-fragment row / B-fragment col
    const int kg   = lane >> 4;          // k-group 0..3
    const int i0   = blockIdx.x * 64;
    const int i    = i0 + w * 16 + lo;   // this lane's attention row

    const float s1v = s1[i];
    const float mm  = s1v + s2m[0];
    const float Mi  = mm > 0.f ? mm : LRELU_ALPHA * mm;   // >= max_j e_ij

    f32x4 acc0 = {0.f, 0.f, 0.f, 0.f};
    f32x4 acc1 = {0.f, 0.f, 0.f, 0.f};
    f32x4 acc2 = {0.f, 0.f, 0.f, 0.f};
    f32x4 acc3 = {0.f, 0.f, 0.f, 0.f};
    float lsum = 0.f;

    const int* arow = adj + (size_t)i * NN;
    const int jstart = blockIdx.y * jlen;
    const int jend   = jstart + jlen;

    for (int j0 = jstart; j0 < jend; j0 += 32) {
        const int kb = j0 + kg * 8;      // this lane's 8 k (j) indices
        const i32x4 A0 = *(const i32x4*)(arow + kb);
        const i32x4 A1 = *(const i32x4*)(arow + kb + 4);
        const f32x4 S0 = *(const f32x4*)(s2 + kb);
        const f32x4 S1 = *(const f32x4*)(s2 + kb + 4);

        short8 af;
        #pragma unroll
        for (int e = 0; e < 8; ++e) {
            const float s2v = (e < 4) ? S0[e] : S1[e & 3];
            const int   av  = (e < 4) ? A0[e] : A1[e & 3];
            const float x   = s1v + s2v;
            const float le  = x > 0.f ? x : LRELU_ALPHA * x;
            const float pe  = (av > 0) ? __expf(le - Mi) : 0.f;
            lsum += pe;
            af[e] = (short)f2bf(pe);
        }

        const unsigned short* hb = ht + kb;  // ht[col][k]: row = col, 8 contiguous k
        const short8 b0 = *(const short8*)(hb + (size_t)(0 * 16 + lo) * NN);
        const short8 b1 = *(const short8*)(hb + (size_t)(1 * 16 + lo) * NN);
        const short8 b2 = *(const short8*)(hb + (size_t)(2 * 16 + lo) * NN);
        const short8 b3 = *(const short8*)(hb + (size_t)(3 * 16 + lo) * NN);

        acc0 = __builtin_amdgcn_mfma_f32_16x16x32_bf16(af, b0, acc0, 0, 0, 0);
        acc1 = __builtin_amdgcn_mfma_f32_16x16x32_bf16(af, b1, acc1, 0, 0, 0);
        acc2 = __builtin_amdgcn_mfma_f32_16x16x32_bf16(af, b2, acc2, 0, 0, 0);
        acc3 = __builtin_amdgcn_mfma_f32_16x16x32_bf16(af, b3, acc3, 0, 0, 0);
    }

    // row-sum of p: reduce across the 4 k-groups (lanes lo, lo+16, lo+32, lo+48)
    lsum += __shfl_xor(lsum, 16, 64);
    lsum += __shfl_xor(lsum, 32, 64);
    if (kg == 0)
        pl[(size_t)blockIdx.y * NN + i] = lsum;

    // C/D layout (m89-verified): col = lane&15, row = (lane>>4)*4 + reg
    float* pa = pacc + ((size_t)blockIdx.y * NN + i0 + w * 16) * FOUT;
    #pragma unroll
    for (int reg = 0; reg < 4; ++reg) {
        const int orow = kg * 4 + reg;
        pa[(size_t)orow * FOUT + 0 * 16 + lo] = acc0[reg];
        pa[(size_t)orow * FOUT + 1 * 16 + lo] = acc1[reg];
        pa[(size_t)orow * FOUT + 2 * 16 + lo] = acc2[reg];
        pa[(size_t)orow * FOUT + 3 * 16 + lo] = acc3[reg];
    }
}

// ---------------------------------------------------------------------------
// Kernel 4: sum partials over j-splits, normalize, elu.
// ---------------------------------------------------------------------------
__global__ __launch_bounds__(256) void gat_reduce(
    const float* __restrict__ pacc, const float* __restrict__ pl,
    float* __restrict__ out, int JS)
{
    const int t = blockIdx.x * 256 + threadIdx.x;   // t < 8192*64
    const int i = t >> 6;
    float l = 0.f, v = 0.f;
    for (int js = 0; js < JS; ++js) {
        l += pl[(size_t)js * NN + i];
        v += pacc[(size_t)js * NN * FOUT + t];
    }
    const float r = v / l;
    out[t] = r > 0.f ? r : expm1f(r);
}

// ---------------------------------------------------------------------------
extern "C" void kernel_launch(void* const* d_in, const int* in_sizes, int n_in,
                              void* d_out, int out_size, void* d_ws, size_t ws_size,
                              hipStream_t stream)
{
    const float* inp = (const float*)d_in[0];
    const int*   adj = (const int*)d_in[1];
    const float* W   = (const float*)d_in[2];
    const float* a   = (const float*)d_in[3];
    float* out = (float*)d_out;

    // workspace carve-up
    char* ws = (char*)d_ws;
    unsigned short* ht = (unsigned short*)ws; ws += (size_t)FOUT * NN * 2;  // 1 MB
    float* s1  = (float*)ws; ws += (size_t)NN * 4;
    float* s2  = (float*)ws; ws += (size_t)NN * 4;
    float* s2m = (float*)ws; ws += 256;
    const size_t fixed = (size_t)(ws - (char*)d_ws);

    int JS = 16;
    while (JS > 1 && fixed + (size_t)JS * NN * 4ull * (FOUT + 1) > ws_size) JS >>= 1;
    const int jlen = NN / JS;

    float* pl   = (float*)ws; ws += (size_t)JS * NN * 4;
    float* pacc = (float*)ws;

    gat_prep  <<<NN / 4, 256, 0, stream>>>(inp, W, a, ht, s1, s2);
    gat_s2max <<<1, 256, 0, stream>>>(s2, s2m);
    gat_attn  <<<dim3(NN / 64, JS), 256, 0, stream>>>(adj, ht, s1, s2, s2m, pacc, pl, jlen);
    gat_reduce<<<(NN * FOUT) / 256, 256, 0, stream>>>(pacc, pl, out, JS);
}

// Round 2
// 137.397 us; speedup vs baseline: 1.0353x; 1.0353x over previous
//
#include <hip/hip_runtime.h>

typedef __attribute__((ext_vector_type(8))) short short8;
typedef __attribute__((ext_vector_type(4))) float f32x4;
typedef __attribute__((ext_vector_type(4))) int   i32x4;

#define NN 8192
#define FIN 128
#define FOUT 64
#define LRELU_ALPHA 0.2f

__device__ __forceinline__ unsigned short f2bf(float x) {
    unsigned u = __float_as_uint(x);
    unsigned r = (u + 0x7FFFu + ((u >> 16) & 1u)) >> 16;  // RNE
    return (unsigned short)r;
}

// ballot-order column permutation within each 64-col group:
// physical col c = 4b + e  <->  virtual col v = 16e + b   (b in [0,16), e in [0,4))
__device__ __forceinline__ unsigned vcol_of(unsigned i) {
    return (i & ~63u) | ((i & 3u) << 4) | ((i & 63u) >> 2);
}

// ---------------------------------------------------------------------------
// Kernel 1: h = inp @ W ; s1 = h@a1 ; s2 = h@a2 ;
//   ht[f][vcol(i)] = bf16(h[i][f]) ; e1v[vcol]=exp(s2) ; e2v[vcol]=exp(a*s2)
// Block: 256 threads = 4 rows x 64 f-lanes. Grid: 2048.
// ---------------------------------------------------------------------------
__global__ __launch_bounds__(256) void gat_prep(
    const float* __restrict__ inp, const float* __restrict__ W,
    const float* __restrict__ a,
    unsigned short* __restrict__ ht, float* __restrict__ s1, float* __restrict__ s2,
    float* __restrict__ e1v, float* __restrict__ e2v)
{
    __shared__ float Wl[FIN * FOUT];   // 32 KB
    __shared__ float il[4 * FIN];      // 2 KB
    const int t = threadIdx.x;
    const int i0 = blockIdx.x * 4;

    #pragma unroll
    for (int k = 0; k < (FIN * FOUT) / 256; ++k)
        Wl[t + 256 * k] = W[t + 256 * k];
    #pragma unroll
    for (int k = 0; k < (4 * FIN) / 256; ++k)
        il[t + 256 * k] = inp[(size_t)i0 * FIN + t + 256 * k];
    __syncthreads();

    const int r = t >> 6;        // local row 0..3
    const int f = t & 63;        // output feature
    float acc = 0.f;
    #pragma unroll 8
    for (int k = 0; k < FIN; ++k)
        acc = fmaf(il[r * FIN + k], Wl[k * FOUT + f], acc);

    float v1 = acc * a[f];
    float v2 = acc * a[FOUT + f];
    #pragma unroll
    for (int off = 32; off; off >>= 1) {
        v1 += __shfl_xor(v1, off, 64);
        v2 += __shfl_xor(v2, off, 64);
    }
    const int i = i0 + r;
    const unsigned vc = vcol_of((unsigned)i);
    if (f == 0) {
        s1[i] = v1;
        s2[i] = v2;
        e1v[vc] = __expf(v2);
        e2v[vc] = __expf(LRELU_ALPHA * v2);
    }
    ht[(size_t)f * NN + vc] = f2bf(acc);
}

// ---------------------------------------------------------------------------
// Kernel 2: s2max = max_j s2[j]  (1 block x 1024)
// ---------------------------------------------------------------------------
__global__ __launch_bounds__(1024) void gat_s2max(const float* __restrict__ s2,
                                                  float* __restrict__ s2m)
{
    __shared__ float red[16];
    float m = -1e30f;
    for (int idx = threadIdx.x; idx < NN; idx += 1024) m = fmaxf(m, s2[idx]);
    #pragma unroll
    for (int off = 32; off; off >>= 1) m = fmaxf(m, __shfl_xor(m, off, 64));
    if ((threadIdx.x & 63) == 0) red[threadIdx.x >> 6] = m;
    __syncthreads();
    if (threadIdx.x == 0) {
        float mm = red[0];
        #pragma unroll
        for (int k = 1; k < 16; ++k) mm = fmaxf(mm, red[k]);
        s2m[0] = mm;
    }
}

// ---------------------------------------------------------------------------
// Kernel 3 (hot): coalesced adj streaming + ballot bitmask + exp-free p,
// MFMA accumulate. Block: 256 = 4 waves x 16 rows. Grid: (128, JS).
// Per wave, per 64-col tile:
//   4 rounds: lane loads int4 of row (16w + 4r + kg), cols jc+4*(lane&15)
//     -> 4 ballots; bit l of ballot_e  <->  row l>>4, col 4*(l&15)+e
//     -> lane (lo,kg) keeps bytes mb0/mb1 = bits v in [32s+8kg, +8) of row lo
//   2 MFMA steps over virtual cols, p = mask ? (x>0 ? c1*e1 : c2*e2) : 0
// ---------------------------------------------------------------------------
__global__ __launch_bounds__(256, 4) void gat_attn(
    const int* __restrict__ adj, const unsigned short* __restrict__ ht,
    const float* __restrict__ s1, const float* __restrict__ e1v,
    const float* __restrict__ e2v, const float* __restrict__ s2m,
    float* __restrict__ pacc, float* __restrict__ pl, int jlen)
{
    const int w    = threadIdx.x >> 6;   // wave 0..3 -> rows w*16..w*16+15
    const int lane = threadIdx.x & 63;
    const int lo   = lane & 15;          // A-frag row / B-frag col
    const int kg   = lane >> 4;          // k-group 0..3
    const int i0   = blockIdx.x * 64;
    const int i    = i0 + w * 16 + lo;   // this lane's attention row

    const float s1v = s1[i];
    const float mm  = s1v + s2m[0];
    const float Mi  = fmaxf(mm, LRELU_ALPHA * mm);      // lrelu(s1+s2max) >= max_j e_ij
    const float c1  = __expf(s1v - Mi);
    const float c2  = __expf(LRELU_ALPHA * s1v - Mi);
    const float Er  = __expf(-s1v);                     // x>0  <=>  e1 > Er

    const int      myr = lo >> 2;                       // round that loads my row
    const unsigned sh  = ((lo & 3) << 4) | ((kg & 1) << 3);

    // loader mapping: round r -> row i0+16w+4r+kg, col jc + 4*(lane&15)
    const int* arow = adj + (size_t)(i0 + w * 16 + kg) * NN + (lane & 15) * 4;

    const int jstart = blockIdx.y * jlen;
    const int jend   = jstart + jlen;

    f32x4 acc0 = {0.f,0.f,0.f,0.f}, acc1 = {0.f,0.f,0.f,0.f};
    f32x4 acc2 = {0.f,0.f,0.f,0.f}, acc3 = {0.f,0.f,0.f,0.f};
    float lsum = 0.f;

    i32x4 A[4];
    #pragma unroll
    for (int r = 0; r < 4; ++r)
        A[r] = *(const i32x4*)(arow + (size_t)r * 4 * NN + jstart);

    for (int jc = jstart; jc < jend; jc += 64) {
        // --- ballots -> per-lane mask bytes ---
        unsigned mb0 = 0, mb1 = 0;
        #pragma unroll
        for (int r = 0; r < 4; ++r) {
            const unsigned long long b0 = __ballot(A[r][0] > 0);
            const unsigned long long b1 = __ballot(A[r][1] > 0);
            const unsigned long long b2 = __ballot(A[r][2] > 0);
            const unsigned long long b3 = __ballot(A[r][3] > 0);
            const unsigned long long sA = (kg & 2) ? b1 : b0;   // e = kg>>1
            const unsigned long long sB = (kg & 2) ? b3 : b2;   // e = 2 + kg>>1
            const unsigned m0 = (unsigned)(sA >> sh) & 0xffu;
            const unsigned m1 = (unsigned)(sB >> sh) & 0xffu;
            mb0 = (myr == r) ? m0 : mb0;
            mb1 = (myr == r) ? m1 : mb1;
        }

        // --- prefetch next tile's adj (stays in flight during MFMA steps) ---
        int jn = jc + 64; if (jn >= jend) jn = jstart;
        #pragma unroll
        for (int r = 0; r < 4; ++r)
            A[r] = *(const i32x4*)(arow + (size_t)r * 4 * NN + jn);

        // --- two MFMA K=32 steps over virtual cols ---
        #pragma unroll
        for (int s = 0; s < 2; ++s) {
            const unsigned mb = s ? mb1 : mb0;
            const int vg = jc + 32 * s + 8 * kg;
            const f32x4 E1a = *(const f32x4*)(e1v + vg);
            const f32x4 E1b = *(const f32x4*)(e1v + vg + 4);
            const f32x4 E2a = *(const f32x4*)(e2v + vg);
            const f32x4 E2b = *(const f32x4*)(e2v + vg + 4);

            short8 af;
            #pragma unroll
            for (int e = 0; e < 8; ++e) {
                const float e1 = (e < 4) ? E1a[e] : E1b[e - 4];
                const float e2 = (e < 4) ? E2a[e] : E2b[e - 4];
                float pv = (e1 > Er) ? c1 * e1 : c2 * e2;
                pv = ((mb >> e) & 1u) ? pv : 0.f;
                lsum += pv;
                af[e] = (short)f2bf(pv);
            }

            const unsigned short* hb = ht + vg;
            const short8 b0 = *(const short8*)(hb + (size_t)(0 * 16 + lo) * NN);
            const short8 b1 = *(const short8*)(hb + (size_t)(1 * 16 + lo) * NN);
            const short8 b2 = *(const short8*)(hb + (size_t)(2 * 16 + lo) * NN);
            const short8 b3 = *(const short8*)(hb + (size_t)(3 * 16 + lo) * NN);

            acc0 = __builtin_amdgcn_mfma_f32_16x16x32_bf16(af, b0, acc0, 0, 0, 0);
            acc1 = __builtin_amdgcn_mfma_f32_16x16x32_bf16(af, b1, acc1, 0, 0, 0);
            acc2 = __builtin_amdgcn_mfma_f32_16x16x32_bf16(af, b2, acc2, 0, 0, 0);
            acc3 = __builtin_amdgcn_mfma_f32_16x16x32_bf16(af, b3, acc3, 0, 0, 0);
        }
    }

    // row-sum of p across the 4 k-groups
    lsum += __shfl_xor(lsum, 16, 64);
    lsum += __shfl_xor(lsum, 32, 64);
    if (kg == 0)
        pl[(size_t)blockIdx.y * NN + i] = lsum;

    // C/D layout (m89-verified): col = lane&15, row = (lane>>4)*4 + reg
    float* pa = pacc + ((size_t)blockIdx.y * NN + i0 + w * 16) * FOUT;
    #pragma unroll
    for (int reg = 0; reg < 4; ++reg) {
        const int orow = kg * 4 + reg;
        pa[(size_t)orow * FOUT + 0 * 16 + lo] = acc0[reg];
        pa[(size_t)orow * FOUT + 1 * 16 + lo] = acc1[reg];
        pa[(size_t)orow * FOUT + 2 * 16 + lo] = acc2[reg];
        pa[(size_t)orow * FOUT + 3 * 16 + lo] = acc3[reg];
    }
}

// ---------------------------------------------------------------------------
// Kernel 4: sum partials over j-splits, normalize, elu.
// ---------------------------------------------------------------------------
__global__ __launch_bounds__(256) void gat_reduce(
    const float* __restrict__ pacc, const float* __restrict__ pl,
    float* __restrict__ out, int JS)
{
    const int t = blockIdx.x * 256 + threadIdx.x;   // t < 8192*64
    const int i = t >> 6;
    float l = 0.f, v = 0.f;
    for (int js = 0; js < JS; ++js) {
        l += pl[(size_t)js * NN + i];
        v += pacc[(size_t)js * NN * FOUT + t];
    }
    const float r = v / l;
    out[t] = r > 0.f ? r : expm1f(r);
}

// ---------------------------------------------------------------------------
extern "C" void kernel_launch(void* const* d_in, const int* in_sizes, int n_in,
                              void* d_out, int out_size, void* d_ws, size_t ws_size,
                              hipStream_t stream)
{
    const float* inp = (const float*)d_in[0];
    const int*   adj = (const int*)d_in[1];
    const float* W   = (const float*)d_in[2];
    const float* a   = (const float*)d_in[3];
    float* out = (float*)d_out;

    // workspace carve-up
    char* ws = (char*)d_ws;
    unsigned short* ht = (unsigned short*)ws; ws += (size_t)FOUT * NN * 2;  // 1 MB
    float* s1  = (float*)ws; ws += (size_t)NN * 4;
    float* s2  = (float*)ws; ws += (size_t)NN * 4;
    float* e1v = (float*)ws; ws += (size_t)NN * 4;
    float* e2v = (float*)ws; ws += (size_t)NN * 4;
    float* s2m = (float*)ws; ws += 256;
    const size_t fixed = (size_t)(ws - (char*)d_ws);

    int JS = 16;
    while (JS > 1 && fixed + (size_t)JS * NN * 4ull * (FOUT + 1) > ws_size) JS >>= 1;
    const int jlen = NN / JS;

    float* pl   = (float*)ws; ws += (size_t)JS * NN * 4;
    float* pacc = (float*)ws;

    gat_prep  <<<NN / 4, 256, 0, stream>>>(inp, W, a, ht, s1, s2, e1v, e2v);
    gat_s2max <<<1, 1024, 0, stream>>>(s2, s2m);
    gat_attn  <<<dim3(NN / 64, JS), 256, 0, stream>>>(adj, ht, s1, e1v, e2v, s2m, pacc, pl, jlen);
    gat_reduce<<<(NN * FOUT) / 256, 256, 0, stream>>>(pacc, pl, out, JS);
}